// Round 5
// baseline (526.078 us; speedup 1.0000x reference)
//
#include <hip/hip_runtime.h>
#include <hip/hip_bf16.h>

typedef unsigned short u16;
typedef unsigned int u32;

#define N_NODES 50000
#define N_EDGES 800000
#define DHID 256
#define NCHUNK 49  // ceil(50000/1024)

typedef __attribute__((ext_vector_type(8))) short bf16x8;
typedef __attribute__((ext_vector_type(4))) float f32x4;

// ---------- helpers ----------
__device__ __forceinline__ u16 f2bf(float f) {
    u32 u = __float_as_uint(f);
    u32 r = (u + 0x7FFFu + ((u >> 16) & 1u)) >> 16;
    return (u16)r;
}
__device__ __forceinline__ float bf2f(u32 bits16) {
    return __uint_as_float(bits16 << 16);
}
__device__ __forceinline__ void gl_lds16(const void* g, void* l) {
    __builtin_amdgcn_global_load_lds(
        (const __attribute__((address_space(1))) u32*)g,
        (__attribute__((address_space(3))) u32*)l, 16, 0, 0);
}

// ---------- graph prep ----------
// zero deg AND the 8 per-tile zero rows of tile-major hs (64 B each)
__global__ void zero_kernel(int* __restrict__ deg, u32* __restrict__ hs32, int n) {
    int i = blockIdx.x * 256 + threadIdx.x;
    if (i < n) deg[i] = 0;
    if (i < 128) {
        int t = i >> 4, w = i & 15;
        hs32[((size_t)t * (N_NODES + 1) + N_NODES) * 16 + w] = 0;
    }
}

__global__ void deg_kernel(const int* __restrict__ dst, int* __restrict__ deg, int E) {
    int e = blockIdx.x * 256 + threadIdx.x;
    if (e < E) atomicAdd(&deg[dst[e]], 1);
}

// chunked scan, step 1: inclusive scan within each 1024-chunk + chunk totals
__global__ __launch_bounds__(1024) void scan1_kernel(const int* __restrict__ deg,
                                                     int* __restrict__ partial,
                                                     int* __restrict__ totals, int n) {
    __shared__ int wsum[16];
    __shared__ int woff[16];
    const int tid = threadIdx.x, lane = tid & 63, wid = tid >> 6;
    const int idx = blockIdx.x * 1024 + tid;
    int v = (idx < n) ? deg[idx] : 0;
    int x = v;
#pragma unroll
    for (int off = 1; off < 64; off <<= 1) {
        int t = __shfl_up(x, off, 64);
        if (lane >= off) x += t;
    }
    if (lane == 63) wsum[wid] = x;
    __syncthreads();
    if (tid == 0) {
        int s = 0;
#pragma unroll
        for (int w = 0; w < 16; ++w) { woff[w] = s; s += wsum[w]; }
    }
    __syncthreads();
    x += woff[wid];
    partial[idx] = x;
    if (tid == 1023) totals[blockIdx.x] = x;
}

// step 2: exclusive scan of the 49 chunk totals — one wave, shuffle scan
__global__ void scan2_kernel(const int* __restrict__ totals, int* __restrict__ chunkoff, int nc) {
    const int lane = threadIdx.x & 63;
    int v = (lane < nc) ? totals[lane] : 0;
    int x = v;
#pragma unroll
    for (int off = 1; off < 64; off <<= 1) {
        int t = __shfl_up(x, off, 64);
        if (lane >= off) x += t;
    }
    if (lane < nc) chunkoff[lane] = x - v;
}

// step 3: exclusive row_ptr = chunkoff + inclusive - deg; cursor copy
__global__ void scan3_kernel(const int* __restrict__ deg, const int* __restrict__ partial,
                             const int* __restrict__ chunkoff, int* __restrict__ rptr,
                             int* __restrict__ cursor, int n) {
    int i = blockIdx.x * 256 + threadIdx.x;
    if (i < n) {
        int e = chunkoff[i >> 10] + partial[i] - deg[i];
        rptr[i] = e;
        cursor[i] = e;
    }
    if (i == 0) rptr[n] = N_EDGES;
}

// CSR fill with u16 column ids (node ids < 65536)
__global__ void fill_kernel(const int* __restrict__ src, const int* __restrict__ dst,
                            int* __restrict__ cursor, u16* __restrict__ col16, int E) {
    int e = blockIdx.x * 256 + threadIdx.x;
    if (e < E) {
        int p = atomicAdd(&cursor[dst[e]], 1);
        col16[p] = (u16)src[e];
    }
}

// ---------- fp32 -> bf16 hi/lo split (4 elems/thread) ----------
__global__ void split_kernel(const float* __restrict__ x, u16* __restrict__ hi,
                             u16* __restrict__ lo, int n4) {
    int i = blockIdx.x * 256 + threadIdx.x;
    if (i < n4) {
        float4 v = ((const float4*)x)[i];
        u16 h0 = f2bf(v.x), h1 = f2bf(v.y), h2 = f2bf(v.z), h3 = f2bf(v.w);
        u16 l0 = f2bf(v.x - bf2f(h0)), l1 = f2bf(v.y - bf2f(h1));
        u16 l2 = f2bf(v.z - bf2f(h2)), l3 = f2bf(v.w - bf2f(h3));
        uint2 hv, lv;
        hv.x = (u32)h0 | ((u32)h1 << 16);
        hv.y = (u32)h2 | ((u32)h3 << 16);
        lv.x = (u32)l0 | ((u32)l1 << 16);
        lv.y = (u32)l2 | ((u32)l3 << 16);
        ((uint2*)hi)[i] = hv;
        ((uint2*)lo)[i] = lv;
    }
}

// ---------- W -> W^T hi/lo split. grid (256, 2), block 256 ----------
__global__ void prepw_kernel(const float* __restrict__ W1, const float* __restrict__ W2,
                             u16* __restrict__ h1, u16* __restrict__ l1,
                             u16* __restrict__ h2, u16* __restrict__ l2) {
    int n = blockIdx.x, k = threadIdx.x;
    const float* W = blockIdx.y ? W2 : W1;
    u16* oh = blockIdx.y ? h2 : h1;
    u16* ol = blockIdx.y ? l2 : l1;
    float v = W[k * 256 + n];
    u16 hh = f2bf(v);
    oh[n * 256 + k] = hh;
    ol[n * 256 + k] = f2bf(v - bf2f(hh));
}

// ---------- GEMM: hs = (A @ W) * rsqrt(deg[row]+1), bf16 TILE-MAJOR out ----------
// out layout: [8 tiles of 32 cols][Nn+1 rows][32] — row Nn per tile stays zero.
__global__ __launch_bounds__(256) void gemm_split_kernel(
    const u16* __restrict__ Ahi, const u16* __restrict__ Alo,
    const u16* __restrict__ Bthi, const u16* __restrict__ Btlo,
    const int* __restrict__ deg, u16* __restrict__ out, int M) {
    __shared__ u16 Ah[128 * 32];
    __shared__ u16 Al[128 * 32];
    __shared__ u16 Bh[128 * 32];
    __shared__ u16 Bl[128 * 32];
    const int tid = threadIdx.x;
    const int wave = tid >> 6;
    const int lane = tid & 63;
    const int wm = wave >> 1, wn = wave & 1;
    const int quad = lane >> 4, l16 = lane & 15;
    const int m0 = blockIdx.x * 128;
    const int n0 = blockIdx.y * 128;

    f32x4 acc[4][4] = {};

    const int row0 = tid >> 2, row1 = (256 + tid) >> 2;
    const int kk = (tid & 3) * 8;
    int ar0 = m0 + row0; if (ar0 >= M) ar0 = M - 1;
    int ar1 = m0 + row1; if (ar1 >= M) ar1 = M - 1;
    const size_t aoff0 = (size_t)ar0 * 256 + kk;
    const size_t aoff1 = (size_t)ar1 * 256 + kk;
    const size_t boff0 = (size_t)(n0 + row0) * 256 + kk;
    const size_t boff1 = (size_t)(n0 + row1) * 256 + kk;
    const size_t l0 = (size_t)(wave * 64) * 8;
    const size_t l1 = (size_t)(256 + wave * 64) * 8;

    for (int ko = 0; ko < 8; ++ko) {
        const int koff = ko * 32;
        __syncthreads();
        gl_lds16(Ahi + aoff0 + koff, &Ah[l0]);
        gl_lds16(Ahi + aoff1 + koff, &Ah[l1]);
        gl_lds16(Alo + aoff0 + koff, &Al[l0]);
        gl_lds16(Alo + aoff1 + koff, &Al[l1]);
        gl_lds16(Bthi + boff0 + koff, &Bh[l0]);
        gl_lds16(Bthi + boff1 + koff, &Bh[l1]);
        gl_lds16(Btlo + boff0 + koff, &Bl[l0]);
        gl_lds16(Btlo + boff1 + koff, &Bl[l1]);
        asm volatile("s_waitcnt vmcnt(0)" ::: "memory");
        __syncthreads();

        bf16x8 ah[4], al[4], bh[4], bl[4];
#pragma unroll
        for (int mi = 0; mi < 4; ++mi) {
            const int r = (wm * 64 + mi * 16 + l16) * 32 + quad * 8;
            ah[mi] = *(const bf16x8*)&Ah[r];
            al[mi] = *(const bf16x8*)&Al[r];
        }
#pragma unroll
        for (int ni = 0; ni < 4; ++ni) {
            const int r = (wn * 64 + ni * 16 + l16) * 32 + quad * 8;
            bh[ni] = *(const bf16x8*)&Bh[r];
            bl[ni] = *(const bf16x8*)&Bl[r];
        }
#pragma unroll
        for (int mi = 0; mi < 4; ++mi)
#pragma unroll
            for (int ni = 0; ni < 4; ++ni) {
                acc[mi][ni] = __builtin_amdgcn_mfma_f32_16x16x32_bf16(ah[mi], bh[ni], acc[mi][ni], 0, 0, 0);
                acc[mi][ni] = __builtin_amdgcn_mfma_f32_16x16x32_bf16(ah[mi], bl[ni], acc[mi][ni], 0, 0, 0);
                acc[mi][ni] = __builtin_amdgcn_mfma_f32_16x16x32_bf16(al[mi], bh[ni], acc[mi][ni], 0, 0, 0);
            }
    }

#pragma unroll
    for (int mi = 0; mi < 4; ++mi) {
#pragma unroll
        for (int r = 0; r < 4; ++r) {
            int row = m0 + wm * 64 + mi * 16 + quad * 4 + r;
            if (row < M) {
                float s = rsqrtf((float)deg[row] + 1.0f);
#pragma unroll
                for (int ni = 0; ni < 4; ++ni) {
                    int c = n0 + wn * 64 + ni * 16 + l16;
                    // tile-major: [c>>5][row][c&31]
                    out[((size_t)(c >> 5) * (N_NODES + 1) + row) * 32 + (c & 31)] =
                        f2bf(acc[mi][ni][r] * s);
                }
            }
        }
    }
}

// ---------- aggregation v4: column-tiled, XCD-pinned ----------
// Task = (node i, tile t) per wave; tile = blockIdx & 7 (XCD round-robin pin).
// hs tile-major [8][Nn+1][32]; per-XCD gather set = 3.2 MB tile + 1.6 MB col16 (L2-fit).
// 8 entry-streams (groups of 8 lanes x 8 B = one 64 B row-slice); chunked u16 index
// loads; depth-2 pipeline; xor(8,16,32) reduce; entry 0 = self, pad = zero row (Nn).
__global__ __launch_bounds__(256) void agg_kernel(
    const u16* __restrict__ hs, const int* __restrict__ rptr, const u16* __restrict__ col16,
    const int* __restrict__ deg, const float* __restrict__ bias,
    u16* __restrict__ out_hi, u16* __restrict__ out_lo, float* __restrict__ out_f,
    int mode, int Nn) {
    const int wave = threadIdx.x >> 6, lane = threadIdx.x & 63;
    const int gid = blockIdx.x;
    const int t = gid & 7;
    const int i = (gid >> 3) * 4 + wave;
    if (i >= Nn) return;
    const int g = lane >> 3;   // entry stream
    const int ql = lane & 7;   // 8 B slice within 64 B row
    const int beg = rptr[i], end = rptr[i + 1];
    const int cnt = end - beg;
    const int nchunk = (cnt + 8) >> 3;  // entries = cnt+1, ceil(entries/8)
    const u16* tbase = hs + (size_t)t * (N_NODES + 1) * 32;

    float a0 = 0, a1 = 0, a2 = 0, a3 = 0;

#define EIDX(c, e)                                                      \
    {                                                                   \
        int pos = (c) * 8 + g;                                          \
        int p = pos - 1;                                                \
        e = (pos == 0) ? i : ((p < cnt) ? (int)col16[beg + p] : Nn);    \
    }
#define LOADV(e, v) v = *(const uint2*)(tbase + (size_t)(e) * 32 + ql * 4);
#define ACCUM(v)                                                        \
    {                                                                   \
        a0 += bf2f(v.x & 0xffffu); a1 += bf2f(v.x >> 16);               \
        a2 += bf2f(v.y & 0xffffu); a3 += bf2f(v.y >> 16);               \
    }

    uint2 v, vn;
    { int e; EIDX(0, e); LOADV(e, v); }
    for (int c = 0; c < nchunk; ++c) {
        if (c + 1 < nchunk) { int e; EIDX(c + 1, e); LOADV(e, vn); }
        ACCUM(v);
        v = vn;
    }
#undef EIDX
#undef LOADV
#undef ACCUM

    // reduce across the 8 streams
    a0 += __shfl_xor(a0, 8, 64); a0 += __shfl_xor(a0, 16, 64); a0 += __shfl_xor(a0, 32, 64);
    a1 += __shfl_xor(a1, 8, 64); a1 += __shfl_xor(a1, 16, 64); a1 += __shfl_xor(a1, 32, 64);
    a2 += __shfl_xor(a2, 8, 64); a2 += __shfl_xor(a2, 16, 64); a2 += __shfl_xor(a2, 32, 64);
    a3 += __shfl_xor(a3, 8, 64); a3 += __shfl_xor(a3, 16, 64); a3 += __shfl_xor(a3, 32, 64);

    const float inv = rsqrtf((float)deg[i] + 1.0f);
    const float4 b = *(const float4*)(bias + t * 32 + ql * 4);
    float r0 = fmaxf(fmaf(a0, inv, b.x), 0.0f);
    float r1 = fmaxf(fmaf(a1, inv, b.y), 0.0f);
    float r2 = fmaxf(fmaf(a2, inv, b.z), 0.0f);
    float r3 = fmaxf(fmaf(a3, inv, b.w), 0.0f);

    const size_t o = (size_t)i * 256 + t * 32 + ql * 4;  // node-major output
    if (mode == 0) {
        u16 h0 = f2bf(r0), h1 = f2bf(r1), h2 = f2bf(r2), h3 = f2bf(r3);
        if (g == 0) {
            uint2 w;
            w.x = (u32)h0 | ((u32)h1 << 16);
            w.y = (u32)h2 | ((u32)h3 << 16);
            *(uint2*)(out_hi + o) = w;
        } else if (g == 1) {
            u16 q0 = f2bf(r0 - bf2f(h0)), q1 = f2bf(r1 - bf2f(h1));
            u16 q2 = f2bf(r2 - bf2f(h2)), q3 = f2bf(r3 - bf2f(h3));
            uint2 w;
            w.x = (u32)q0 | ((u32)q1 << 16);
            w.y = (u32)q2 | ((u32)q3 << 16);
            *(uint2*)(out_lo + o) = w;
        }
    } else {
        if (g == 0) *(float4*)(out_f + o) = make_float4(r0, r1, r2, r3);
    }
}

extern "C" void kernel_launch(void* const* d_in, const int* in_sizes, int n_in,
                              void* d_out, int out_size, void* d_ws, size_t ws_size,
                              hipStream_t stream) {
    const float* x = (const float*)d_in[0];
    const int* ei = (const int*)d_in[1];
    const float* W1 = (const float*)d_in[2];
    const float* b1 = (const float*)d_in[3];
    const float* W2 = (const float*)d_in[4];
    const float* b2 = (const float*)d_in[5];
    float* out = (float*)d_out;

    const int Nn = N_NODES, E = N_EDGES;
    const int* srcp = ei;
    const int* dstp = ei + E;

    // d_out doubles as scratch: exactly fits hi+lo bf16 node-feature buffers.
    u16* Ahi = (u16*)d_out;
    u16* Alo = Ahi + (size_t)Nn * DHID;

    char* p = (char*)d_ws;
    auto take = [&](size_t bytes) -> void* {
        void* r = (void*)p;
        p += (bytes + 255) & ~(size_t)255;
        return r;
    };
    u16* hs      = (u16*)take((size_t)8 * (Nn + 1) * 32 * 2);  // tile-major, 25.6 MB
    u16* col16   = (u16*)take((size_t)E * 2);                   // 1.6 MB
    int* deg     = (int*)take((size_t)Nn * 4);
    int* cursor  = (int*)take((size_t)Nn * 4);
    int* rptr    = (int*)take((size_t)(Nn + 1) * 4);
    int* partial = (int*)take((size_t)NCHUNK * 1024 * 4);
    int* totals  = (int*)take(64 * 4);
    int* chunkoff= (int*)take(64 * 4);
    u16* W1t_hi  = (u16*)take(256 * 256 * 2);
    u16* W1t_lo  = (u16*)take(256 * 256 * 2);
    u16* W2t_hi  = (u16*)take(256 * 256 * 2);
    u16* W2t_lo  = (u16*)take(256 * 256 * 2);

    const int nb = (Nn + 255) / 256;
    zero_kernel<<<nb, 256, 0, stream>>>(deg, (u32*)hs, Nn);
    deg_kernel<<<E / 256, 256, 0, stream>>>(dstp, deg, E);
    scan1_kernel<<<NCHUNK, 1024, 0, stream>>>(deg, partial, totals, Nn);
    scan2_kernel<<<1, 64, 0, stream>>>(totals, chunkoff, NCHUNK);
    scan3_kernel<<<nb, 256, 0, stream>>>(deg, partial, chunkoff, rptr, cursor, Nn);
    fill_kernel<<<E / 256, 256, 0, stream>>>(srcp, dstp, cursor, col16, E);

    split_kernel<<<(Nn * DHID / 4 + 255) / 256, 256, 0, stream>>>(x, Ahi, Alo, Nn * DHID / 4);
    prepw_kernel<<<dim3(256, 2), 256, 0, stream>>>(W1, W2, W1t_hi, W1t_lo, W2t_hi, W2t_lo);

    const int gm = (Nn + 127) / 128;  // 391
    const int aggblocks = ((Nn + 3) / 4) * 8;  // 100000: (node-group, tile)
    // layer 1
    gemm_split_kernel<<<dim3(gm, 2), 256, 0, stream>>>(Ahi, Alo, W1t_hi, W1t_lo, deg, hs, Nn);
    agg_kernel<<<aggblocks, 256, 0, stream>>>(hs, rptr, col16, deg, b1, Ahi, Alo, nullptr, 0, Nn);
    // layer 2
    gemm_split_kernel<<<dim3(gm, 2), 256, 0, stream>>>(Ahi, Alo, W2t_hi, W2t_lo, deg, hs, Nn);
    agg_kernel<<<aggblocks, 256, 0, stream>>>(hs, rptr, col16, deg, b2, nullptr, nullptr, out, 1, Nn);
}

// Round 6
// 383.787 us; speedup vs baseline: 1.3708x; 1.3708x over previous
//
#include <hip/hip_runtime.h>
#include <hip/hip_bf16.h>

typedef unsigned short u16;
typedef unsigned int u32;

#define N_NODES 50000
#define N_EDGES 800000
#define DHID 256
#define NCHUNK 49  // ceil(50000/1024)

typedef __attribute__((ext_vector_type(8))) short bf16x8;
typedef __attribute__((ext_vector_type(4))) float f32x4;
typedef __attribute__((ext_vector_type(2))) float f32x2;

// ---------- helpers ----------
__device__ __forceinline__ u16 f2bf(float f) {
    u32 u = __float_as_uint(f);
    u32 r = (u + 0x7FFFu + ((u >> 16) & 1u)) >> 16;
    return (u16)r;
}
__device__ __forceinline__ float bf2f(u32 bits16) {
    return __uint_as_float(bits16 << 16);
}
__device__ __forceinline__ void gl_lds16(const void* g, void* l) {
    __builtin_amdgcn_global_load_lds(
        (const __attribute__((address_space(1))) u32*)g,
        (__attribute__((address_space(3))) u32*)l, 16, 0, 0);
}

// ---------- fused prep: split x (hi/lo), zero deg + hs zero-row, W^T hi/lo ----------
// grid = 12500 (split) + 196 (zero) + 512 (prepw), block 256
#define SPLIT_BLKS 12500
#define ZERO_BLKS 196
__global__ void prep_fused(const float* __restrict__ x, u16* __restrict__ hi,
                           u16* __restrict__ lo,
                           const float* __restrict__ W1, const float* __restrict__ W2,
                           u16* __restrict__ h1, u16* __restrict__ l1,
                           u16* __restrict__ h2, u16* __restrict__ l2,
                           int* __restrict__ deg, u32* __restrict__ hszero) {
    const int b = blockIdx.x, tid = threadIdx.x;
    if (b < SPLIT_BLKS) {
        int i = b * 256 + tid;  // n4 = 3.2M exact
        float4 v = ((const float4*)x)[i];
        u16 h0 = f2bf(v.x), h1v = f2bf(v.y), h2v = f2bf(v.z), h3 = f2bf(v.w);
        u16 l0 = f2bf(v.x - bf2f(h0)), l1v = f2bf(v.y - bf2f(h1v));
        u16 l2v = f2bf(v.z - bf2f(h2v)), l3 = f2bf(v.w - bf2f(h3));
        uint2 hv, lv;
        hv.x = (u32)h0 | ((u32)h1v << 16);
        hv.y = (u32)h2v | ((u32)h3 << 16);
        lv.x = (u32)l0 | ((u32)l1v << 16);
        lv.y = (u32)l2v | ((u32)l3 << 16);
        ((uint2*)hi)[i] = hv;
        ((uint2*)lo)[i] = lv;
    } else if (b < SPLIT_BLKS + ZERO_BLKS) {
        int j = (b - SPLIT_BLKS) * 256 + tid;
        if (j < N_NODES) deg[j] = 0;
        if (j < 128) hszero[j] = 0;  // 512 B zero row at hs[N_NODES]
    } else {
        int idx = b - (SPLIT_BLKS + ZERO_BLKS);  // 0..511
        int y = idx >> 8, n = idx & 255, k = tid;
        const float* W = y ? W2 : W1;
        u16* oh = y ? h2 : h1;
        u16* ol = y ? l2 : l1;
        float v = W[k * 256 + n];
        u16 hh = f2bf(v);
        oh[n * 256 + k] = hh;
        ol[n * 256 + k] = f2bf(v - bf2f(hh));
    }
}

__global__ void deg_kernel(const int* __restrict__ dst, int* __restrict__ deg, int E) {
    int e = blockIdx.x * 256 + threadIdx.x;
    if (e < E) atomicAdd(&deg[dst[e]], 1);
}

// chunked scan, step 1: inclusive scan within each 1024-chunk + chunk totals
__global__ __launch_bounds__(1024) void scan1_kernel(const int* __restrict__ deg,
                                                     int* __restrict__ partial,
                                                     int* __restrict__ totals, int n) {
    __shared__ int wsum[16];
    __shared__ int woff[16];
    const int tid = threadIdx.x, lane = tid & 63, wid = tid >> 6;
    const int idx = blockIdx.x * 1024 + tid;
    int v = (idx < n) ? deg[idx] : 0;
    int x = v;
#pragma unroll
    for (int off = 1; off < 64; off <<= 1) {
        int t = __shfl_up(x, off, 64);
        if (lane >= off) x += t;
    }
    if (lane == 63) wsum[wid] = x;
    __syncthreads();
    if (tid == 0) {
        int s = 0;
#pragma unroll
        for (int w = 0; w < 16; ++w) { woff[w] = s; s += wsum[w]; }
    }
    __syncthreads();
    x += woff[wid];
    partial[idx] = x;
    if (tid == 1023) totals[blockIdx.x] = x;
}

// step 2+3 fused: each block re-scans the 49 totals in wave 0, then
// rptr[i] = chunkoff + partial[i] - deg[i]. Block covers 256 nodes = single chunk.
__global__ void scan3_kernel(const int* __restrict__ deg, const int* __restrict__ partial,
                             const int* __restrict__ totals, int* __restrict__ rptr,
                             int* __restrict__ cursor, int n) {
    __shared__ int coff_s;
    const int tid = threadIdx.x;
    const int mychunk = blockIdx.x >> 2;  // (256*b..256*b+255)>>10 is constant
    if (tid < 64) {
        int v = (tid < NCHUNK) ? totals[tid] : 0;
        int x = v;
#pragma unroll
        for (int off = 1; off < 64; off <<= 1) {
            int t = __shfl_up(x, off, 64);
            if (tid >= off) x += t;
        }
        if (tid == mychunk) coff_s = x - v;  // exclusive offset of my chunk
    }
    __syncthreads();
    int i = blockIdx.x * 256 + tid;
    if (i < n) {
        int e = coff_s + partial[i] - deg[i];
        rptr[i] = e;
        cursor[i] = e;
    }
    if (i == 0) rptr[n] = N_EDGES;
}

// CSR fill with u16 column ids (node ids < 65536)
__global__ void fill_kernel(const int* __restrict__ src, const int* __restrict__ dst,
                            int* __restrict__ cursor, u16* __restrict__ col16, int E) {
    int e = blockIdx.x * 256 + threadIdx.x;
    if (e < E) {
        int p = atomicAdd(&cursor[dst[e]], 1);
        col16[p] = (u16)src[e];
    }
}

// ---------- GEMM: hs = (A @ W) * rsqrt(deg[row]+1), bf16 node-major out ----------
__global__ __launch_bounds__(256) void gemm_split_kernel(
    const u16* __restrict__ Ahi, const u16* __restrict__ Alo,
    const u16* __restrict__ Bthi, const u16* __restrict__ Btlo,
    const int* __restrict__ deg, u16* __restrict__ out, int M) {
    __shared__ u16 Ah[128 * 32];
    __shared__ u16 Al[128 * 32];
    __shared__ u16 Bh[128 * 32];
    __shared__ u16 Bl[128 * 32];
    const int tid = threadIdx.x;
    const int wave = tid >> 6;
    const int lane = tid & 63;
    const int wm = wave >> 1, wn = wave & 1;
    const int quad = lane >> 4, l16 = lane & 15;
    const int m0 = blockIdx.x * 128;
    const int n0 = blockIdx.y * 128;

    f32x4 acc[4][4] = {};

    const int row0 = tid >> 2, row1 = (256 + tid) >> 2;
    const int kk = (tid & 3) * 8;
    int ar0 = m0 + row0; if (ar0 >= M) ar0 = M - 1;
    int ar1 = m0 + row1; if (ar1 >= M) ar1 = M - 1;
    const size_t aoff0 = (size_t)ar0 * 256 + kk;
    const size_t aoff1 = (size_t)ar1 * 256 + kk;
    const size_t boff0 = (size_t)(n0 + row0) * 256 + kk;
    const size_t boff1 = (size_t)(n0 + row1) * 256 + kk;
    const size_t l0 = (size_t)(wave * 64) * 8;
    const size_t l1 = (size_t)(256 + wave * 64) * 8;

    for (int ko = 0; ko < 8; ++ko) {
        const int koff = ko * 32;
        __syncthreads();
        gl_lds16(Ahi + aoff0 + koff, &Ah[l0]);
        gl_lds16(Ahi + aoff1 + koff, &Ah[l1]);
        gl_lds16(Alo + aoff0 + koff, &Al[l0]);
        gl_lds16(Alo + aoff1 + koff, &Al[l1]);
        gl_lds16(Bthi + boff0 + koff, &Bh[l0]);
        gl_lds16(Bthi + boff1 + koff, &Bh[l1]);
        gl_lds16(Btlo + boff0 + koff, &Bl[l0]);
        gl_lds16(Btlo + boff1 + koff, &Bl[l1]);
        asm volatile("s_waitcnt vmcnt(0)" ::: "memory");
        __syncthreads();

        bf16x8 ah[4], al[4], bh[4], bl[4];
#pragma unroll
        for (int mi = 0; mi < 4; ++mi) {
            const int r = (wm * 64 + mi * 16 + l16) * 32 + quad * 8;
            ah[mi] = *(const bf16x8*)&Ah[r];
            al[mi] = *(const bf16x8*)&Al[r];
        }
#pragma unroll
        for (int ni = 0; ni < 4; ++ni) {
            const int r = (wn * 64 + ni * 16 + l16) * 32 + quad * 8;
            bh[ni] = *(const bf16x8*)&Bh[r];
            bl[ni] = *(const bf16x8*)&Bl[r];
        }
#pragma unroll
        for (int mi = 0; mi < 4; ++mi)
#pragma unroll
            for (int ni = 0; ni < 4; ++ni) {
                acc[mi][ni] = __builtin_amdgcn_mfma_f32_16x16x32_bf16(ah[mi], bh[ni], acc[mi][ni], 0, 0, 0);
                acc[mi][ni] = __builtin_amdgcn_mfma_f32_16x16x32_bf16(ah[mi], bl[ni], acc[mi][ni], 0, 0, 0);
                acc[mi][ni] = __builtin_amdgcn_mfma_f32_16x16x32_bf16(al[mi], bh[ni], acc[mi][ni], 0, 0, 0);
            }
    }

#pragma unroll
    for (int mi = 0; mi < 4; ++mi) {
#pragma unroll
        for (int r = 0; r < 4; ++r) {
            int row = m0 + wm * 64 + mi * 16 + quad * 4 + r;
            if (row < M) {
                float s = rsqrtf((float)deg[row] + 1.0f);
#pragma unroll
                for (int ni = 0; ni < 4; ++ni) {
                    int c = n0 + wn * 64 + ni * 16 + l16;
                    out[(size_t)row * 256 + c] = f2bf(acc[mi][ni][r] * s);
                }
            }
        }
    }
}

// ---------- aggregation v5: R3 skeleton + packed pk_add accumulate + depth-2 batches ----
// one wave per node; lane covers cols 4l..4l+3 (uint2 = 8 B). Entry 0 = self,
// then neighbors (u16 ids), padded to x4 with zero row (hs[Nn]).
__global__ __launch_bounds__(256) void agg_kernel(
    const u16* __restrict__ hs, const int* __restrict__ rptr, const u16* __restrict__ col16,
    const int* __restrict__ deg, const float* __restrict__ bias,
    u16* __restrict__ out_hi, u16* __restrict__ out_lo, float* __restrict__ out_f,
    int mode, int Nn) {
    const int wave = threadIdx.x >> 6, lane = threadIdx.x & 63;
    const int i = blockIdx.x * 4 + wave;
    if (i >= Nn) return;

    const int beg = rptr[i], end = rptr[i + 1];
    const int cnt = end - beg;
    int entry = Nn;  // zero-row pad
    if (lane == 0) entry = i;
    else if (lane - 1 < cnt) entry = (int)col16[beg + lane - 1];
    int entries = cnt + 1;
    if (entries > 64) entries = 64;
    const int nb = (entries + 3) >> 2;
    const size_t lofs = (size_t)lane * 4;

    f32x2 a01 = {0.f, 0.f}, a23 = {0.f, 0.f};

#define ISSUE(b, x0, x1, x2, x3)                                                \
    {                                                                           \
        int e0 = __builtin_amdgcn_readlane(entry, (b) * 4 + 0);                 \
        int e1 = __builtin_amdgcn_readlane(entry, (b) * 4 + 1);                 \
        int e2 = __builtin_amdgcn_readlane(entry, (b) * 4 + 2);                 \
        int e3 = __builtin_amdgcn_readlane(entry, (b) * 4 + 3);                 \
        x0 = *(const uint2*)(hs + (size_t)e0 * 256 + lofs);                     \
        x1 = *(const uint2*)(hs + (size_t)e1 * 256 + lofs);                     \
        x2 = *(const uint2*)(hs + (size_t)e2 * 256 + lofs);                     \
        x3 = *(const uint2*)(hs + (size_t)e3 * 256 + lofs);                     \
    }
#define ACCUM(v)                                                                \
    {                                                                           \
        f32x2 p0, p1;                                                           \
        p0.x = __uint_as_float(v.x << 16);                                      \
        p0.y = __uint_as_float(v.x & 0xffff0000u);                              \
        p1.x = __uint_as_float(v.y << 16);                                      \
        p1.y = __uint_as_float(v.y & 0xffff0000u);                              \
        a01 += p0; a23 += p1;                                                   \
    }

    uint2 c0, c1, c2, c3, n0v, n1v, n2v, n3v;
    ISSUE(0, c0, c1, c2, c3);
    for (int b = 0; b < nb; ++b) {
        const bool more = (b + 1 < nb);
        if (more) ISSUE(b + 1, n0v, n1v, n2v, n3v);
        ACCUM(c0); ACCUM(c1); ACCUM(c2); ACCUM(c3);
        if (more) { c0 = n0v; c1 = n1v; c2 = n2v; c3 = n3v; }
    }
    // rare tail: deg > 63
    for (int j = beg + 63; j < end; ++j) {
        int s = (int)col16[j];
        uint2 v = *(const uint2*)(hs + (size_t)s * 256 + lofs);
        ACCUM(v);
    }
#undef ISSUE
#undef ACCUM

    const float inv = rsqrtf((float)deg[i] + 1.0f);
    float4 bb = *(const float4*)(bias + lane * 4);
    float r0 = fmaxf(fmaf(a01.x, inv, bb.x), 0.0f);
    float r1 = fmaxf(fmaf(a01.y, inv, bb.y), 0.0f);
    float r2 = fmaxf(fmaf(a23.x, inv, bb.z), 0.0f);
    float r3 = fmaxf(fmaf(a23.y, inv, bb.w), 0.0f);
    const size_t o = (size_t)i * 256 + lane * 4;
    if (mode == 0) {
        u16 h0 = f2bf(r0), h1 = f2bf(r1), h2 = f2bf(r2), h3 = f2bf(r3);
        u16 l0 = f2bf(r0 - bf2f(h0)), l1 = f2bf(r1 - bf2f(h1));
        u16 l2 = f2bf(r2 - bf2f(h2)), l3 = f2bf(r3 - bf2f(h3));
        uint2 hv, lv;
        hv.x = (u32)h0 | ((u32)h1 << 16);
        hv.y = (u32)h2 | ((u32)h3 << 16);
        lv.x = (u32)l0 | ((u32)l1 << 16);
        lv.y = (u32)l2 | ((u32)l3 << 16);
        *(uint2*)(out_hi + o) = hv;
        *(uint2*)(out_lo + o) = lv;
    } else {
        *(float4*)(out_f + o) = make_float4(r0, r1, r2, r3);
    }
}

extern "C" void kernel_launch(void* const* d_in, const int* in_sizes, int n_in,
                              void* d_out, int out_size, void* d_ws, size_t ws_size,
                              hipStream_t stream) {
    const float* x = (const float*)d_in[0];
    const int* ei = (const int*)d_in[1];
    const float* W1 = (const float*)d_in[2];
    const float* b1 = (const float*)d_in[3];
    const float* W2 = (const float*)d_in[4];
    const float* b2 = (const float*)d_in[5];
    float* out = (float*)d_out;

    const int Nn = N_NODES, E = N_EDGES;
    const int* srcp = ei;
    const int* dstp = ei + E;

    // d_out doubles as scratch: exactly fits hi+lo bf16 node-feature buffers.
    u16* Ahi = (u16*)d_out;
    u16* Alo = Ahi + (size_t)Nn * DHID;

    char* p = (char*)d_ws;
    auto take = [&](size_t bytes) -> void* {
        void* r = (void*)p;
        p += (bytes + 255) & ~(size_t)255;
        return r;
    };
    u16* hs      = (u16*)take((size_t)(Nn + 1) * DHID * 2);  // +1 zero row
    u16* col16   = (u16*)take((size_t)E * 2);
    int* deg     = (int*)take((size_t)Nn * 4);
    int* cursor  = (int*)take((size_t)Nn * 4);
    int* rptr    = (int*)take((size_t)(Nn + 1) * 4);
    int* partial = (int*)take((size_t)NCHUNK * 1024 * 4);
    int* totals  = (int*)take(64 * 4);
    u16* W1t_hi  = (u16*)take(256 * 256 * 2);
    u16* W1t_lo  = (u16*)take(256 * 256 * 2);
    u16* W2t_hi  = (u16*)take(256 * 256 * 2);
    u16* W2t_lo  = (u16*)take(256 * 256 * 2);

    prep_fused<<<SPLIT_BLKS + ZERO_BLKS + 512, 256, 0, stream>>>(
        x, Ahi, Alo, W1, W2, W1t_hi, W1t_lo, W2t_hi, W2t_lo,
        deg, (u32*)(hs + (size_t)Nn * DHID));
    deg_kernel<<<E / 256, 256, 0, stream>>>(dstp, deg, E);
    scan1_kernel<<<NCHUNK, 1024, 0, stream>>>(deg, partial, totals, Nn);
    scan3_kernel<<<ZERO_BLKS, 256, 0, stream>>>(deg, partial, totals, rptr, cursor, Nn);
    fill_kernel<<<E / 256, 256, 0, stream>>>(srcp, dstp, cursor, col16, E);

    const int gm = (Nn + 127) / 128;  // 391
    // layer 1
    gemm_split_kernel<<<dim3(gm, 2), 256, 0, stream>>>(Ahi, Alo, W1t_hi, W1t_lo, deg, hs, Nn);
    agg_kernel<<<(Nn + 3) / 4, 256, 0, stream>>>(hs, rptr, col16, deg, b1, Ahi, Alo, nullptr, 0, Nn);
    // layer 2
    gemm_split_kernel<<<dim3(gm, 2), 256, 0, stream>>>(Ahi, Alo, W2t_hi, W2t_lo, deg, hs, Nn);
    agg_kernel<<<(Nn + 3) / 4, 256, 0, stream>>>(hs, rptr, col16, deg, b2, nullptr, nullptr, out, 1, Nn);
}

// Round 7
// 342.867 us; speedup vs baseline: 1.5343x; 1.1193x over previous
//
#include <hip/hip_runtime.h>
#include <hip/hip_bf16.h>

typedef unsigned short u16;
typedef unsigned int u32;

#define N_NODES 50000
#define N_EDGES 800000
#define DHID 256
#define NCHUNK 49  // ceil(50000/1024)

typedef __attribute__((ext_vector_type(8))) _Float16 f16x8;
typedef __attribute__((ext_vector_type(4))) float f32x4;
typedef __attribute__((ext_vector_type(2))) float f32x2;

// ---------- helpers ----------
__device__ __forceinline__ u16 f2bf(float f) {
    u32 u = __float_as_uint(f);
    u32 r = (u + 0x7FFFu + ((u >> 16) & 1u)) >> 16;
    return (u16)r;
}
__device__ __forceinline__ float bf2f(u32 bits16) {
    return __uint_as_float(bits16 << 16);
}
__device__ __forceinline__ u16 f2h(float f) {
    _Float16 h = (_Float16)f;
    union { _Float16 h; u16 u; } c; c.h = h;
    return c.u;
}
__device__ __forceinline__ void gl_lds16(const void* g, void* l) {
    __builtin_amdgcn_global_load_lds(
        (const __attribute__((address_space(1))) u32*)g,
        (__attribute__((address_space(3))) u32*)l, 16, 0, 0);
}

// ---------- fused prep: x -> f16, zero deg + hs zero-row, W -> W^T f16 ----------
// grid = 12500 (split) + 196 (zero) + 512 (prepw), block 256
#define SPLIT_BLKS 12500
#define ZERO_BLKS 196
__global__ void prep_fused(const float* __restrict__ x, u16* __restrict__ xf,
                           const float* __restrict__ W1, const float* __restrict__ W2,
                           u16* __restrict__ W1t, u16* __restrict__ W2t,
                           int* __restrict__ deg, u32* __restrict__ hszero) {
    const int b = blockIdx.x, tid = threadIdx.x;
    if (b < SPLIT_BLKS) {
        int i = b * 256 + tid;  // n4 = 3.2M exact
        float4 v = ((const float4*)x)[i];
        u16 h0 = f2h(v.x), h1 = f2h(v.y), h2 = f2h(v.z), h3 = f2h(v.w);
        uint2 hv;
        hv.x = (u32)h0 | ((u32)h1 << 16);
        hv.y = (u32)h2 | ((u32)h3 << 16);
        ((uint2*)xf)[i] = hv;
    } else if (b < SPLIT_BLKS + ZERO_BLKS) {
        int j = (b - SPLIT_BLKS) * 256 + tid;
        if (j < N_NODES) deg[j] = 0;
        if (j < 128) hszero[j] = 0;  // 512 B zero row at hs[N_NODES]
    } else {
        int idx = b - (SPLIT_BLKS + ZERO_BLKS);  // 0..511
        int y = idx >> 8, n = idx & 255, k = tid;
        const float* W = y ? W2 : W1;
        u16* o = y ? W2t : W1t;
        o[n * 256 + k] = f2h(W[k * 256 + n]);
    }
}

__global__ void deg_kernel(const int* __restrict__ dst, int* __restrict__ deg, int E) {
    int e = blockIdx.x * 256 + threadIdx.x;
    if (e < E) atomicAdd(&deg[dst[e]], 1);
}

// chunked scan, step 1: inclusive scan within each 1024-chunk + chunk totals
__global__ __launch_bounds__(1024) void scan1_kernel(const int* __restrict__ deg,
                                                     int* __restrict__ partial,
                                                     int* __restrict__ totals, int n) {
    __shared__ int wsum[16];
    __shared__ int woff[16];
    const int tid = threadIdx.x, lane = tid & 63, wid = tid >> 6;
    const int idx = blockIdx.x * 1024 + tid;
    int v = (idx < n) ? deg[idx] : 0;
    int x = v;
#pragma unroll
    for (int off = 1; off < 64; off <<= 1) {
        int t = __shfl_up(x, off, 64);
        if (lane >= off) x += t;
    }
    if (lane == 63) wsum[wid] = x;
    __syncthreads();
    if (tid == 0) {
        int s = 0;
#pragma unroll
        for (int w = 0; w < 16; ++w) { woff[w] = s; s += wsum[w]; }
    }
    __syncthreads();
    x += woff[wid];
    partial[idx] = x;
    if (tid == 1023) totals[blockIdx.x] = x;
}

// step 2+3 fused: each block re-scans the 49 totals in wave 0, then
// rptr[i] = chunkoff + partial[i] - deg[i]. Block covers 256 nodes = single chunk.
__global__ void scan3_kernel(const int* __restrict__ deg, const int* __restrict__ partial,
                             const int* __restrict__ totals, int* __restrict__ rptr,
                             int* __restrict__ cursor, int n) {
    __shared__ int coff_s;
    const int tid = threadIdx.x;
    const int mychunk = blockIdx.x >> 2;
    if (tid < 64) {
        int v = (tid < NCHUNK) ? totals[tid] : 0;
        int x = v;
#pragma unroll
        for (int off = 1; off < 64; off <<= 1) {
            int t = __shfl_up(x, off, 64);
            if (tid >= off) x += t;
        }
        if (tid == mychunk) coff_s = x - v;
    }
    __syncthreads();
    int i = blockIdx.x * 256 + tid;
    if (i < n) {
        int e = coff_s + partial[i] - deg[i];
        rptr[i] = e;
        cursor[i] = e;
    }
    if (i == 0) rptr[n] = N_EDGES;
}

// CSR fill with u16 column ids (node ids < 65536)
__global__ void fill_kernel(const int* __restrict__ src, const int* __restrict__ dst,
                            int* __restrict__ cursor, u16* __restrict__ col16, int E) {
    int e = blockIdx.x * 256 + threadIdx.x;
    if (e < E) {
        int p = atomicAdd(&cursor[dst[e]], 1);
        col16[p] = (u16)src[e];
    }
}

// ---------- GEMM (f16 single-product): hs = (A @ W) * rsqrt(deg[row]+1), bf16 out ----------
// A f16 [Nn][256] row-major (tail clamped); W^T f16 [256][256] (n-major). K=256.
__global__ __launch_bounds__(256) void gemm_f16_kernel(
    const u16* __restrict__ Af, const u16* __restrict__ Bt,
    const int* __restrict__ deg, u16* __restrict__ out, int M) {
    __shared__ u16 As[128 * 32];
    __shared__ u16 Bs[128 * 32];
    const int tid = threadIdx.x;
    const int wave = tid >> 6;
    const int lane = tid & 63;
    const int wm = wave >> 1, wn = wave & 1;
    const int quad = lane >> 4, l16 = lane & 15;
    const int m0 = blockIdx.x * 128;
    const int n0 = blockIdx.y * 128;

    f32x4 acc[4][4] = {};

    const int row0 = tid >> 2, row1 = (256 + tid) >> 2;
    const int kk = (tid & 3) * 8;
    int ar0 = m0 + row0; if (ar0 >= M) ar0 = M - 1;
    int ar1 = m0 + row1; if (ar1 >= M) ar1 = M - 1;
    const size_t aoff0 = (size_t)ar0 * 256 + kk;
    const size_t aoff1 = (size_t)ar1 * 256 + kk;
    const size_t boff0 = (size_t)(n0 + row0) * 256 + kk;
    const size_t boff1 = (size_t)(n0 + row1) * 256 + kk;
    const size_t l0 = (size_t)(wave * 64) * 8;
    const size_t l1 = (size_t)(256 + wave * 64) * 8;

    for (int ko = 0; ko < 8; ++ko) {
        const int koff = ko * 32;
        __syncthreads();
        gl_lds16(Af + aoff0 + koff, &As[l0]);
        gl_lds16(Af + aoff1 + koff, &As[l1]);
        gl_lds16(Bt + boff0 + koff, &Bs[l0]);
        gl_lds16(Bt + boff1 + koff, &Bs[l1]);
        asm volatile("s_waitcnt vmcnt(0)" ::: "memory");
        __syncthreads();

        f16x8 af[4], bf[4];
#pragma unroll
        for (int mi = 0; mi < 4; ++mi)
            af[mi] = *(const f16x8*)&As[(wm * 64 + mi * 16 + l16) * 32 + quad * 8];
#pragma unroll
        for (int ni = 0; ni < 4; ++ni)
            bf[ni] = *(const f16x8*)&Bs[(wn * 64 + ni * 16 + l16) * 32 + quad * 8];
#pragma unroll
        for (int mi = 0; mi < 4; ++mi)
#pragma unroll
            for (int ni = 0; ni < 4; ++ni)
                acc[mi][ni] = __builtin_amdgcn_mfma_f32_16x16x32_f16(af[mi], bf[ni], acc[mi][ni], 0, 0, 0);
    }

#pragma unroll
    for (int mi = 0; mi < 4; ++mi) {
#pragma unroll
        for (int r = 0; r < 4; ++r) {
            int row = m0 + wm * 64 + mi * 16 + quad * 4 + r;
            if (row < M) {
                float s = rsqrtf((float)deg[row] + 1.0f);
#pragma unroll
                for (int ni = 0; ni < 4; ++ni) {
                    int c = n0 + wn * 64 + ni * 16 + l16;
                    out[(size_t)row * 256 + c] = f2bf(acc[mi][ni][r] * s);
                }
            }
        }
    }
}

// ---------- aggregation (R6 winner): packed pk_add accumulate, depth-2 batches ----------
// one wave per node; lane covers cols 4l..4l+3 (uint2 = 8 B, bf16 rows). Entry 0 = self,
// then neighbors (u16 ids), padded to x4 with zero row (hs[Nn]).
// mode 0: write f16 (feeds next GEMM). mode 1: write fp32 to d_out.
__global__ __launch_bounds__(256) void agg_kernel(
    const u16* __restrict__ hs, const int* __restrict__ rptr, const u16* __restrict__ col16,
    const int* __restrict__ deg, const float* __restrict__ bias,
    u16* __restrict__ out_f16, float* __restrict__ out_f,
    int mode, int Nn) {
    const int wave = threadIdx.x >> 6, lane = threadIdx.x & 63;
    const int i = blockIdx.x * 4 + wave;
    if (i >= Nn) return;

    const int beg = rptr[i], end = rptr[i + 1];
    const int cnt = end - beg;
    int entry = Nn;  // zero-row pad
    if (lane == 0) entry = i;
    else if (lane - 1 < cnt) entry = (int)col16[beg + lane - 1];
    int entries = cnt + 1;
    if (entries > 64) entries = 64;
    const int nb = (entries + 3) >> 2;
    const size_t lofs = (size_t)lane * 4;

    f32x2 a01 = {0.f, 0.f}, a23 = {0.f, 0.f};

#define ISSUE(b, x0, x1, x2, x3)                                                \
    {                                                                           \
        int e0 = __builtin_amdgcn_readlane(entry, (b) * 4 + 0);                 \
        int e1 = __builtin_amdgcn_readlane(entry, (b) * 4 + 1);                 \
        int e2 = __builtin_amdgcn_readlane(entry, (b) * 4 + 2);                 \
        int e3 = __builtin_amdgcn_readlane(entry, (b) * 4 + 3);                 \
        x0 = *(const uint2*)(hs + (size_t)e0 * 256 + lofs);                     \
        x1 = *(const uint2*)(hs + (size_t)e1 * 256 + lofs);                     \
        x2 = *(const uint2*)(hs + (size_t)e2 * 256 + lofs);                     \
        x3 = *(const uint2*)(hs + (size_t)e3 * 256 + lofs);                     \
    }
#define ACCUM(v)                                                                \
    {                                                                           \
        f32x2 p0, p1;                                                           \
        p0.x = __uint_as_float(v.x << 16);                                      \
        p0.y = __uint_as_float(v.x & 0xffff0000u);                              \
        p1.x = __uint_as_float(v.y << 16);                                      \
        p1.y = __uint_as_float(v.y & 0xffff0000u);                              \
        a01 += p0; a23 += p1;                                                   \
    }

    uint2 c0, c1, c2, c3, n0v, n1v, n2v, n3v;
    ISSUE(0, c0, c1, c2, c3);
    for (int b = 0; b < nb; ++b) {
        const bool more = (b + 1 < nb);
        if (more) ISSUE(b + 1, n0v, n1v, n2v, n3v);
        ACCUM(c0); ACCUM(c1); ACCUM(c2); ACCUM(c3);
        if (more) { c0 = n0v; c1 = n1v; c2 = n2v; c3 = n3v; }
    }
    // rare tail: deg > 63
    for (int j = beg + 63; j < end; ++j) {
        int s = (int)col16[j];
        uint2 v = *(const uint2*)(hs + (size_t)s * 256 + lofs);
        ACCUM(v);
    }
#undef ISSUE
#undef ACCUM

    const float inv = rsqrtf((float)deg[i] + 1.0f);
    float4 bb = *(const float4*)(bias + lane * 4);
    float r0 = fmaxf(fmaf(a01.x, inv, bb.x), 0.0f);
    float r1 = fmaxf(fmaf(a01.y, inv, bb.y), 0.0f);
    float r2 = fmaxf(fmaf(a23.x, inv, bb.z), 0.0f);
    float r3 = fmaxf(fmaf(a23.y, inv, bb.w), 0.0f);
    const size_t o = (size_t)i * 256 + lane * 4;
    if (mode == 0) {
        u16 h0 = f2h(r0), h1 = f2h(r1), h2 = f2h(r2), h3 = f2h(r3);
        uint2 w;
        w.x = (u32)h0 | ((u32)h1 << 16);
        w.y = (u32)h2 | ((u32)h3 << 16);
        *(uint2*)(out_f16 + o) = w;
    } else {
        *(float4*)(out_f + o) = make_float4(r0, r1, r2, r3);
    }
}

extern "C" void kernel_launch(void* const* d_in, const int* in_sizes, int n_in,
                              void* d_out, int out_size, void* d_ws, size_t ws_size,
                              hipStream_t stream) {
    const float* x = (const float*)d_in[0];
    const int* ei = (const int*)d_in[1];
    const float* W1 = (const float*)d_in[2];
    const float* b1 = (const float*)d_in[3];
    const float* W2 = (const float*)d_in[4];
    const float* b2 = (const float*)d_in[5];
    float* out = (float*)d_out;

    const int Nn = N_NODES, E = N_EDGES;
    const int* srcp = ei;
    const int* dstp = ei + E;

    // d_out doubles as scratch: f16 GEMM A buffer (25.6 MB of the 51.2 MB).
    u16* Af = (u16*)d_out;

    char* p = (char*)d_ws;
    auto take = [&](size_t bytes) -> void* {
        void* r = (void*)p;
        p += (bytes + 255) & ~(size_t)255;
        return r;
    };
    u16* hs      = (u16*)take((size_t)(Nn + 1) * DHID * 2);  // bf16, +1 zero row
    u16* col16   = (u16*)take((size_t)E * 2);
    int* deg     = (int*)take((size_t)Nn * 4);
    int* cursor  = (int*)take((size_t)Nn * 4);
    int* rptr    = (int*)take((size_t)(Nn + 1) * 4);
    int* partial = (int*)take((size_t)NCHUNK * 1024 * 4);
    int* totals  = (int*)take(64 * 4);
    u16* W1t     = (u16*)take(256 * 256 * 2);
    u16* W2t     = (u16*)take(256 * 256 * 2);

    prep_fused<<<SPLIT_BLKS + ZERO_BLKS + 512, 256, 0, stream>>>(
        x, Af, W1, W2, W1t, W2t, deg, (u32*)(hs + (size_t)Nn * DHID));
    deg_kernel<<<E / 256, 256, 0, stream>>>(dstp, deg, E);
    scan1_kernel<<<NCHUNK, 1024, 0, stream>>>(deg, partial, totals, Nn);
    scan3_kernel<<<ZERO_BLKS, 256, 0, stream>>>(deg, partial, totals, rptr, cursor, Nn);
    fill_kernel<<<E / 256, 256, 0, stream>>>(srcp, dstp, cursor, col16, E);

    const int gm = (Nn + 127) / 128;  // 391
    // layer 1
    gemm_f16_kernel<<<dim3(gm, 2), 256, 0, stream>>>(Af, W1t, deg, hs, Nn);
    agg_kernel<<<(Nn + 3) / 4, 256, 0, stream>>>(hs, rptr, col16, deg, b1, Af, nullptr, 0, Nn);
    // layer 2
    gemm_f16_kernel<<<dim3(gm, 2), 256, 0, stream>>>(Af, W2t, deg, hs, Nn);
    agg_kernel<<<(Nn + 3) / 4, 256, 0, stream>>>(hs, rptr, col16, deg, b2, nullptr, out, 1, Nn);
}